// Round 3
// baseline (532.248 us; speedup 1.0000x reference)
//
#include <hip/hip_runtime.h>
#include <hip/hip_bf16.h>

typedef __bf16 bf16x8 __attribute__((ext_vector_type(8)));
typedef __bf16 bf16x4 __attribute__((ext_vector_type(4)));
typedef float  f32x4  __attribute__((ext_vector_type(4)));

#define N_ROWS 32768
#define D_DIM  256
#define K_PROT 2048

// ws layout (float offsets)
#define WS_Z2    0
#define WS_INVN  32768
#define WS_P2    65536
#define WS_ACC   67584                 // 2 floats (sum of row-mins, sum of col-mins)
#define WS_RP    67600                 // row-min partials [16][32768] f32 = 2 MB
#define WS_CP    (67600 + 524288)      // col-min partials [256][2048] f32 = 2 MB
#define WS_ZB    (67600 + 1048576)     // bf16 Z copy: 32768*256 bf16 (16B-aligned)
#define WS_PB    (67600 + 1048576 + 4194304)  // bf16 P copy

// out layout (float offsets)
#define OUT_X0   0UL
#define OUT_X1   8388608UL
#define OUT_XMAP 16777216UL
#define OUT_CVAE 83886080UL
#define OUT_PROT 83886081UL

__device__ __forceinline__ void gload16(const __bf16* gsrc, const __bf16* ldst) {
    auto g = (const __attribute__((address_space(1))) unsigned int*)(unsigned long long)gsrc;
    auto l = (__attribute__((address_space(3))) unsigned int*)(unsigned long long)ldst;
    __builtin_amdgcn_global_load_lds(g, l, 16, 0, 0);
}

// ---------------- K12: fused row prep for Z (norms, copies, bf16) and P (norms, bf16) ----------------
__global__ __launch_bounds__(256) void k12_rows(
    const float* __restrict__ Z, const float* __restrict__ P,
    float* __restrict__ out0, float* __restrict__ out1,
    float* __restrict__ z2, float* __restrict__ invn,
    __bf16* __restrict__ Zb,
    float* __restrict__ p2, __bf16* __restrict__ Pb,
    float* __restrict__ accw)
{
    int b    = blockIdx.x;
    int lane = threadIdx.x & 63;
    if (b == 0 && threadIdx.x < 2) accw[threadIdx.x] = 0.0f;   // init loss accumulators
    if (b < (N_ROWS/4)) {
        int row  = (b << 2) + (threadIdx.x >> 6);
        size_t base = (size_t)row * D_DIM;
        float4 v = ((const float4*)(Z + base))[lane];
        float ss = v.x*v.x + v.y*v.y + v.z*v.z + v.w*v.w;
        #pragma unroll
        for (int d = 32; d >= 1; d >>= 1) ss += __shfl_xor(ss, d);
        float inv = 1.0f / fmaxf(sqrtf(ss), 1e-12f);
        ((float4*)(out0 + base))[lane] = v;
        float4 xv; xv.x = v.x*inv; xv.y = v.y*inv; xv.z = v.z*inv; xv.w = v.w*inv;
        ((float4*)(out1 + base))[lane] = xv;
        bf16x4 bv; bv[0]=(__bf16)v.x; bv[1]=(__bf16)v.y; bv[2]=(__bf16)v.z; bv[3]=(__bf16)v.w;
        ((bf16x4*)(Zb + base))[lane] = bv;
        if (lane == 0) { z2[row] = ss; invn[row] = inv; }
    } else {
        int row  = ((b - (N_ROWS/4)) << 2) + (threadIdx.x >> 6);
        size_t base = (size_t)row * D_DIM;
        float4 v = ((const float4*)(P + base))[lane];
        float ss = v.x*v.x + v.y*v.y + v.z*v.z + v.w*v.w;
        #pragma unroll
        for (int d = 32; d >= 1; d >>= 1) ss += __shfl_xor(ss, d);
        bf16x4 bv; bv[0]=(__bf16)v.x; bv[1]=(__bf16)v.y; bv[2]=(__bf16)v.z; bv[3]=(__bf16)v.w;
        ((bf16x4*)(Pb + base))[lane] = bv;
        if (lane == 0) { p2[row] = ss; }
    }
}

// ---------------- K3: bf16 MFMA GEMM G = Zb * Pb^T + fused epilogue ----------------
// IDENTICAL to round 2. This round's experiment: k3 is launched TWICE (it is
// idempotent: xmap/rp/cp are pure functions of inputs, no atomics). The dur_us
// delta vs round 2 (432.7) measures k3's true in-graph cost:
//   dur ~= 432.7 + k3  -> kernels are timed; attack k3 next.
//   dur ~= 432.7       -> measured window is pinned by harness poison fills.
#define BM 128
#define BN 128
#define BK 64

__global__ __launch_bounds__(256, 3) void k3_gemm(
    const __bf16* __restrict__ Zb, const __bf16* __restrict__ Pb,
    const float* __restrict__ z2, const float* __restrict__ p2,
    const float* __restrict__ invn,
    float* __restrict__ xmap,
    float* __restrict__ rp, float* __restrict__ cp)
{
    __shared__ __bf16 As[BM * BK];   // 16 KB, rows of 128 B, contiguous
    __shared__ __bf16 Bs[BN * BK];   // 16 KB

    const int tid  = threadIdx.x;
    // XCD swizzle: hw-consecutive-mod-8 blocks (same XCD) -> contiguous logical chunk
    const int wg   = (blockIdx.x & 7) * 512 + (blockIdx.x >> 3);
    const int bn   = wg & 15;   // 16 n-blocks
    const int bm   = wg >> 4;   // 256 m-blocks
    const int lane = tid & 63;
    const int wave = tid >> 6;
    const int wm   = wave >> 1;
    const int wn   = wave & 1;
    const int l15  = lane & 15;
    const int quad = lane >> 4;

    const int m0 = bm * BM;
    const int n0 = bn * BN;

    f32x4 acc[4][4];
    #pragma unroll
    for (int i = 0; i < 4; i++)
        #pragma unroll
        for (int j = 0; j < 4; j++)
            #pragma unroll
            for (int r = 0; r < 4; r++) acc[i][j][r] = 0.0f;

    const int ch_row[4] = {
        ((0*4 + wave)*64 + lane) >> 3, ((1*4 + wave)*64 + lane) >> 3,
        ((2*4 + wave)*64 + lane) >> 3, ((3*4 + wave)*64 + lane) >> 3 };
    const int ch_c = lane & 7;

    for (int kt = 0; kt < D_DIM; kt += BK) {
        #pragma unroll
        for (int it = 0; it < 4; it++) {
            const __bf16* aS = Zb + (size_t)(m0 + ch_row[it]) * D_DIM + kt + ch_c * 8;
            const __bf16* bS = Pb + (size_t)(n0 + ch_row[it]) * D_DIM + kt + ch_c * 8;
            gload16(aS, As + (it*4 + wave) * 512);
            gload16(bS, Bs + (it*4 + wave) * 512);
        }
        __syncthreads();   // drains vmcnt(0): staging visible

        #pragma unroll
        for (int s = 0; s < 2; s++) {
            bf16x8 af[4], bfr[4];
            #pragma unroll
            for (int i = 0; i < 4; i++)
                af[i] = *(const bf16x8*)(As + (wm*64 + i*16 + l15) * BK + s*32 + quad*8);
            #pragma unroll
            for (int j = 0; j < 4; j++)
                bfr[j] = *(const bf16x8*)(Bs + (wn*64 + j*16 + l15) * BK + s*32 + quad*8);
            #pragma unroll
            for (int i = 0; i < 4; i++)
                #pragma unroll
                for (int j = 0; j < 4; j++)
                    acc[i][j] = __builtin_amdgcn_mfma_f32_16x16x32_bf16(af[i], bfr[j], acc[i][j], 0, 0, 0);
        }
        __syncthreads();   // protect LDS before next stage
    }

    // ---- epilogue ----
    float invr[16], zzr[16];
    #pragma unroll
    for (int i = 0; i < 4; i++)
        #pragma unroll
        for (int r = 0; r < 4; r++) {
            int gm = m0 + wm*64 + i*16 + quad*4 + r;
            invr[i*4+r] = invn[gm];
            zzr[i*4+r]  = z2[gm];
        }
    float pp[4];
    #pragma unroll
    for (int j = 0; j < 4; j++) pp[j] = p2[n0 + wn*64 + j*16 + l15];

    float cminv[4] = {3.0e38f, 3.0e38f, 3.0e38f, 3.0e38f};
    float rvv[16];

    #pragma unroll
    for (int i = 0; i < 4; i++) {
        #pragma unroll
        for (int r = 0; r < 4; r++) {
            int gm = m0 + wm*64 + i*16 + quad*4 + r;
            float zi = zzr[i*4+r], iv = invr[i*4+r];
            size_t orow = (size_t)gm * K_PROT + n0 + wn*64 + l15;
            float rv = 3.0e38f;
            #pragma unroll
            for (int j = 0; j < 4; j++) {
                float g = acc[i][j][r];
                xmap[orow + j*16] = g * iv;
                float d2 = fmaxf(zi + pp[j] - 2.0f*g, 0.0f);
                rv = fminf(rv, d2);
                cminv[j] = fminf(cminv[j], d2);
            }
            #pragma unroll
            for (int s = 1; s < 16; s <<= 1) rv = fminf(rv, __shfl_xor(rv, s));
            rvv[i*4+r] = rv;
        }
    }
    float cvv[4];
    #pragma unroll
    for (int j = 0; j < 4; j++) {
        float cv = cminv[j];
        cv = fminf(cv, __shfl_xor(cv, 16));
        cv = fminf(cv, __shfl_xor(cv, 32));
        cvv[j] = cv;
    }

    // block-level combine in LDS (As is dead after the K-loop's trailing barrier)
    float* srow = (float*)As;        // 128 row-mins
    float* scol = srow + 128;        // 128 col-mins
    if (wn == 0 && l15 == 0) {
        #pragma unroll
        for (int i = 0; i < 4; i++)
            #pragma unroll
            for (int r = 0; r < 4; r++)
                srow[wm*64 + i*16 + quad*4 + r] = rvv[i*4+r];
    }
    if (wm == 0 && quad == 0) {
        #pragma unroll
        for (int j = 0; j < 4; j++) scol[wn*64 + j*16 + l15] = cvv[j];
    }
    __syncthreads();
    if (wn == 1 && l15 == 0) {
        #pragma unroll
        for (int i = 0; i < 4; i++)
            #pragma unroll
            for (int r = 0; r < 4; r++) {
                int idx = wm*64 + i*16 + quad*4 + r;
                srow[idx] = fminf(srow[idx], rvv[i*4+r]);
            }
    }
    if (wm == 1 && quad == 0) {
        #pragma unroll
        for (int j = 0; j < 4; j++) {
            int c = wn*64 + j*16 + l15;
            scol[c] = fminf(scol[c], cvv[j]);
        }
    }
    __syncthreads();
    if (tid < 128)       rp[(size_t)bn * N_ROWS + m0 + tid] = srow[tid];
    else if (tid < 256)  cp[(size_t)bm * K_PROT + n0 + (tid - 128)] = scol[tid - 128];
}

// ---------------- K4: reduce partials (min over tiles, sqrt, sum) ----------------
__global__ __launch_bounds__(256) void k4_reduce(
    const float* __restrict__ rp, const float* __restrict__ cp,
    float* __restrict__ accw)
{
    __shared__ float sbuf[160];
    int b = blockIdx.x, t = threadIdx.x;
    int lane = t & 63, w = t >> 6;
    if (b < 64) {
        float a = 0.0f;
        #pragma unroll
        for (int rr = 0; rr < 2; rr++) {
            int row = b*512 + rr*256 + t;
            float m = 3.0e38f;
            #pragma unroll
            for (int k = 0; k < 16; k++) m = fminf(m, rp[(size_t)k * N_ROWS + row]);
            a += sqrtf(m);
        }
        #pragma unroll
        for (int d = 32; d >= 1; d >>= 1) a += __shfl_xor(a, d);
        if (lane == 0) sbuf[w] = a;
        __syncthreads();
        if (t == 0) atomicAdd(accw + 0, sbuf[0] + sbuf[1] + sbuf[2] + sbuf[3]);
    } else {
        int col  = (b - 64) * 128 + (t & 127);
        int half = t >> 7;
        float m = 3.0e38f;
        for (int k = half*128; k < half*128 + 128; k++)
            m = fminf(m, cp[(size_t)k * K_PROT + col]);
        if (half == 0) sbuf[t] = m;
        __syncthreads();
        if (half == 1) sbuf[t - 128] = fminf(sbuf[t - 128], m);
        __syncthreads();
        if (t < 128) {
            float s = sqrtf(sbuf[t]);
            #pragma unroll
            for (int d = 32; d >= 1; d >>= 1) s += __shfl_xor(s, d);
            if (lane == 0) sbuf[128 + (t >> 6)] = s;
        }
        __syncthreads();
        if (t == 0) atomicAdd(accw + 1, sbuf[128] + sbuf[129]);
    }
}

// ---------------- K5: finalize scalar outputs ----------------
__global__ void k5_final(
    const float* __restrict__ accw,
    const float* __restrict__ recon, const float* __restrict__ kl,
    const float* __restrict__ mmd, float* __restrict__ out)
{
    out[OUT_CVAE] = recon[0] + 0.5f*kl[0] + mmd[0];
    out[OUT_PROT] = 0.5f*(accw[0] / (float)N_ROWS) + 0.5f*(accw[1] / (float)K_PROT);
}

extern "C" void kernel_launch(void* const* d_in, const int* in_sizes, int n_in,
                              void* d_out, int out_size, void* d_ws, size_t ws_size,
                              hipStream_t stream)
{
    const float* Z     = (const float*)d_in[0];
    const float* P     = (const float*)d_in[1];
    const float* recon = (const float*)d_in[2];
    const float* kl    = (const float*)d_in[3];
    const float* mmd   = (const float*)d_in[4];
    float* out = (float*)d_out;
    float* ws  = (float*)d_ws;

    float* z2   = ws + WS_Z2;
    float* invn = ws + WS_INVN;
    float* p2   = ws + WS_P2;
    float* accw = ws + WS_ACC;
    float* rp   = ws + WS_RP;
    float* cp   = ws + WS_CP;
    __bf16* Zb = (__bf16*)(ws + WS_ZB);
    __bf16* Pb = (__bf16*)(ws + WS_PB);

    hipLaunchKernelGGL(k12_rows, dim3(N_ROWS/4 + K_PROT/4), dim3(256), 0, stream,
                       Z, P, out + OUT_X0, out + OUT_X1, z2, invn, Zb, p2, Pb, accw);
    // PROBE: k3 launched twice (idempotent). dur_us delta vs round 2 == k3's
    // true in-graph cost. See kernel comment for the decision tree.
    hipLaunchKernelGGL(k3_gemm, dim3((N_ROWS/BM)*(K_PROT/BN)), dim3(256), 0, stream,
                       Zb, Pb, z2, p2, invn, out + OUT_XMAP, rp, cp);
    hipLaunchKernelGGL(k3_gemm, dim3((N_ROWS/BM)*(K_PROT/BN)), dim3(256), 0, stream,
                       Zb, Pb, z2, p2, invn, out + OUT_XMAP, rp, cp);
    hipLaunchKernelGGL(k4_reduce, dim3(80), dim3(256), 0, stream, rp, cp, accw);
    hipLaunchKernelGGL(k5_final, dim3(1), dim3(1), 0, stream, accw, recon, kl, mmd, out);
}

// Round 6
// 450.369 us; speedup vs baseline: 1.1818x; 1.1818x over previous
//
#include <hip/hip_runtime.h>
#include <hip/hip_bf16.h>

typedef __bf16 bf16x8 __attribute__((ext_vector_type(8)));
typedef __bf16 bf16x4 __attribute__((ext_vector_type(4)));
typedef float  f32x4  __attribute__((ext_vector_type(4)));

#define N_ROWS 32768
#define D_DIM  256
#define K_PROT 2048

// ws layout (float offsets)
#define WS_Z2    0
#define WS_INVN  32768
#define WS_P2    65536
#define WS_ACC   67584                 // 2 floats (sum of row-mins, sum of col-mins)
#define WS_RP    67600                 // row-min partials [16][32768] f32 = 2 MB
#define WS_CP    (67600 + 524288)      // col-min partials [256][2048] f32 = 2 MB
#define WS_ZB    (67600 + 1048576)     // bf16 Z copy: 32768*256 bf16 (16B-aligned)
#define WS_PB    (67600 + 1048576 + 4194304)  // bf16 P copy

// out layout (float offsets)
#define OUT_X0   0UL
#define OUT_X1   8388608UL
#define OUT_XMAP 16777216UL
#define OUT_CVAE 83886080UL
#define OUT_PROT 83886081UL

__device__ __forceinline__ void gload16(const __bf16* gsrc, const __bf16* ldst) {
    auto g = (const __attribute__((address_space(1))) unsigned int*)(unsigned long long)gsrc;
    auto l = (__attribute__((address_space(3))) unsigned int*)(unsigned long long)ldst;
    __builtin_amdgcn_global_load_lds(g, l, 16, 0, 0);
}

// ---------------- K12: fused row prep for Z (norms, copies, bf16) and P (norms, bf16) ----------------
__global__ __launch_bounds__(256) void k12_rows(
    const float* __restrict__ Z, const float* __restrict__ P,
    float* __restrict__ out0, float* __restrict__ out1,
    float* __restrict__ z2, float* __restrict__ invn,
    __bf16* __restrict__ Zb,
    float* __restrict__ p2, __bf16* __restrict__ Pb,
    float* __restrict__ accw)
{
    int b    = blockIdx.x;
    int lane = threadIdx.x & 63;
    if (b == 0 && threadIdx.x < 2) accw[threadIdx.x] = 0.0f;   // init loss accumulators
    if (b < (N_ROWS/4)) {
        int row  = (b << 2) + (threadIdx.x >> 6);
        size_t base = (size_t)row * D_DIM;
        float4 v = ((const float4*)(Z + base))[lane];
        float ss = v.x*v.x + v.y*v.y + v.z*v.z + v.w*v.w;
        #pragma unroll
        for (int d = 32; d >= 1; d >>= 1) ss += __shfl_xor(ss, d);
        float inv = 1.0f / fmaxf(sqrtf(ss), 1e-12f);
        ((float4*)(out0 + base))[lane] = v;
        float4 xv; xv.x = v.x*inv; xv.y = v.y*inv; xv.z = v.z*inv; xv.w = v.w*inv;
        ((float4*)(out1 + base))[lane] = xv;
        bf16x4 bv; bv[0]=(__bf16)v.x; bv[1]=(__bf16)v.y; bv[2]=(__bf16)v.z; bv[3]=(__bf16)v.w;
        ((bf16x4*)(Zb + base))[lane] = bv;
        if (lane == 0) { z2[row] = ss; invn[row] = inv; }
    } else {
        int row  = ((b - (N_ROWS/4)) << 2) + (threadIdx.x >> 6);
        size_t base = (size_t)row * D_DIM;
        float4 v = ((const float4*)(P + base))[lane];
        float ss = v.x*v.x + v.y*v.y + v.z*v.z + v.w*v.w;
        #pragma unroll
        for (int d = 32; d >= 1; d >>= 1) ss += __shfl_xor(ss, d);
        bf16x4 bv; bv[0]=(__bf16)v.x; bv[1]=(__bf16)v.y; bv[2]=(__bf16)v.z; bv[3]=(__bf16)v.w;
        ((bf16x4*)(Pb + base))[lane] = bv;
        if (lane == 0) { p2[row] = ss; }
    }
}

// ---------------- K3: bf16 MFMA GEMM G = Zb * Pb^T + fused epilogue ----------------
// BISECT of round-4 (two container deaths): keep the ideas, drop ALL inline asm
// and raw barriers.
//  (1) minimum 2-phase double-buffer (catalog T3 recipe): STAGE(next) issued
//      BEFORE current tile's ds_read+MFMA; one __syncthreads per tile. The
//      implicit vmcnt(0) drain lands after ~400cy of covering work instead of
//      immediately after issue. LDS 64 KB -> (256,2).
//  (2) xmap stores via per-wave LDS repack (plain HIP, compiler-fenced) ->
//      global_store_dwordx4 full-line writes.
#define BM 128
#define BN 128
#define BK 64

__global__ __launch_bounds__(256, 2) void k3_gemm(
    const __bf16* __restrict__ Zb, const __bf16* __restrict__ Pb,
    const float* __restrict__ z2, const float* __restrict__ p2,
    const float* __restrict__ invn,
    float* __restrict__ xmap,
    float* __restrict__ rp, float* __restrict__ cp)
{
    __shared__ __bf16 As[2][BM * BK];   // 2 x 16 KB
    __shared__ __bf16 Bs[2][BN * BK];   // 2 x 16 KB

    const int tid  = threadIdx.x;
    // XCD swizzle: hw-consecutive-mod-8 blocks (same XCD) -> contiguous logical chunk
    const int wg   = (blockIdx.x & 7) * 512 + (blockIdx.x >> 3);
    const int bn   = wg & 15;   // 16 n-blocks
    const int bm   = wg >> 4;   // 256 m-blocks
    const int lane = tid & 63;
    const int wave = tid >> 6;
    const int wm   = wave >> 1;
    const int wn   = wave & 1;
    const int l15  = lane & 15;
    const int quad = lane >> 4;

    const int m0 = bm * BM;
    const int n0 = bn * BN;

    f32x4 acc[4][4];
    #pragma unroll
    for (int i = 0; i < 4; i++)
        #pragma unroll
        for (int j = 0; j < 4; j++)
            #pragma unroll
            for (int r = 0; r < 4; r++) acc[i][j][r] = 0.0f;

    // staging: chunk = (it*4+wave)*64 + lane (16B units).
    const int ch_row[4] = {
        ((0*4 + wave)*64 + lane) >> 3, ((1*4 + wave)*64 + lane) >> 3,
        ((2*4 + wave)*64 + lane) >> 3, ((3*4 + wave)*64 + lane) >> 3 };
    const int ch_c = lane & 7;

    #define STAGE(buf, kt)                                                            \
        {                                                                             \
            _Pragma("unroll")                                                         \
            for (int it = 0; it < 4; it++) {                                          \
                const __bf16* aS = Zb + (size_t)(m0 + ch_row[it]) * D_DIM + (kt) + ch_c * 8; \
                const __bf16* bS = Pb + (size_t)(n0 + ch_row[it]) * D_DIM + (kt) + ch_c * 8; \
                gload16(aS, As[buf] + (it*4 + wave) * 512);                           \
                gload16(bS, Bs[buf] + (it*4 + wave) * 512);                           \
            }                                                                         \
        }

    STAGE(0, 0);
    __syncthreads();                       // tile 0 resident

    #pragma unroll
    for (int t = 0; t < 4; t++) {
        const int cur = t & 1;
        if (t + 1 < 4) STAGE(cur ^ 1, (t + 1) * BK);   // prefetch next tile under compute

        bf16x8 af[2][4], bfr[2][4];
        #pragma unroll
        for (int s = 0; s < 2; s++) {
            #pragma unroll
            for (int i = 0; i < 4; i++)
                af[s][i] = *(const bf16x8*)(As[cur] + (wm*64 + i*16 + l15) * BK + s*32 + quad*8);
            #pragma unroll
            for (int j = 0; j < 4; j++)
                bfr[s][j] = *(const bf16x8*)(Bs[cur] + (wn*64 + j*16 + l15) * BK + s*32 + quad*8);
        }
        #pragma unroll
        for (int s = 0; s < 2; s++)
            #pragma unroll
            for (int i = 0; i < 4; i++)
                #pragma unroll
                for (int j = 0; j < 4; j++)
                    acc[i][j] = __builtin_amdgcn_mfma_f32_16x16x32_bf16(af[s][i], bfr[s][j], acc[i][j], 0, 0, 0);

        __syncthreads();   // drains prefetch (tile t+1 resident) + all reads of buf[cur] done
    }
    #undef STAGE

    // ---- epilogue ----
    // C/D layout (m89-verified): col(n) = lane&15, row(m) = quad*4 + reg
    // Mins over SQUARED distances (sqrt is monotone, applied in k4); all values >= 0.
    float invr[16], zzr[16];
    #pragma unroll
    for (int i = 0; i < 4; i++)
        #pragma unroll
        for (int r = 0; r < 4; r++) {
            int gm = m0 + wm*64 + i*16 + quad*4 + r;
            invr[i*4+r] = invn[gm];
            zzr[i*4+r]  = z2[gm];
        }
    float pp[4];
    #pragma unroll
    for (int j = 0; j < 4; j++) pp[j] = p2[n0 + wn*64 + j*16 + l15];

    float cminv[4] = {3.0e38f, 3.0e38f, 3.0e38f, 3.0e38f};
    float rvv[16];

    #pragma unroll
    for (int i = 0; i < 4; i++) {
        #pragma unroll
        for (int r = 0; r < 4; r++) {
            float zi = zzr[i*4+r];
            float rv = 3.0e38f;
            #pragma unroll
            for (int j = 0; j < 4; j++) {
                float g = acc[i][j][r];
                float d2 = fmaxf(zi + pp[j] - 2.0f*g, 0.0f);
                rv = fminf(rv, d2);
                cminv[j] = fminf(cminv[j], d2);
            }
            #pragma unroll
            for (int s = 1; s < 16; s <<= 1) rv = fminf(rv, __shfl_xor(rv, s));
            rvv[i*4+r] = rv;   // valid on all lanes (xor butterfly)
        }
    }
    float cvv[4];
    #pragma unroll
    for (int j = 0; j < 4; j++) {
        float cv = cminv[j];
        cv = fminf(cv, __shfl_xor(cv, 16));
        cv = fminf(cv, __shfl_xor(cv, 32));
        cvv[j] = cv;           // valid on all lanes
    }

    // xmap via per-wave LDS repack (As is dead: K-loop's final __syncthreads ensures
    // all waves' LDS reads are complete; each wave uses only its own 4 KB region so
    // no cross-wave sync is needed; within-wave write->read ordering is compiler-fenced).
    // Index XOR ((row>>2)<<3): bijective involution applied identically on write and
    // read; spreads the 4 row-quads across banks, XOR bit is outside the f32x4 span.
    {
        float* ep = ((float*)As) + wave * 1024;
        #pragma unroll
        for (int i = 0; i < 4; i++) {
            #pragma unroll
            for (int r = 0; r < 4; r++) {
                float iv = invr[i*4+r];
                #pragma unroll
                for (int j = 0; j < 4; j++) {
                    int widx = ((quad*4 + r)*64 + j*16 + l15) ^ (quad << 3);
                    ep[widx] = acc[i][j][r] * iv;
                }
            }
            #pragma unroll
            for (int p = 0; p < 4; p++) {
                int ridx = (p*256 + (lane>>4)*64 + (lane&15)*4) ^ (p << 3);
                f32x4 vv = *(const f32x4*)(ep + ridx);
                int grow = m0 + wm*64 + i*16 + p*4 + (lane>>4);
                *(f32x4*)(xmap + (size_t)grow * K_PROT + n0 + wn*64 + (lane&15)*4) = vv;
            }
        }
    }

    // block-level combine in LDS (Bs region; disjoint from per-wave ep regions)
    float* srow = (float*)Bs;        // 128 row-mins
    float* scol = srow + 128;        // 128 col-mins
    if (wn == 0 && l15 == 0) {
        #pragma unroll
        for (int i = 0; i < 4; i++)
            #pragma unroll
            for (int r = 0; r < 4; r++)
                srow[wm*64 + i*16 + quad*4 + r] = rvv[i*4+r];
    }
    if (wm == 0 && quad == 0) {
        #pragma unroll
        for (int j = 0; j < 4; j++) scol[wn*64 + j*16 + l15] = cvv[j];
    }
    __syncthreads();
    if (wn == 1 && l15 == 0) {
        #pragma unroll
        for (int i = 0; i < 4; i++)
            #pragma unroll
            for (int r = 0; r < 4; r++) {
                int idx = wm*64 + i*16 + quad*4 + r;
                srow[idx] = fminf(srow[idx], rvv[i*4+r]);
            }
    }
    if (wm == 1 && quad == 0) {
        #pragma unroll
        for (int j = 0; j < 4; j++) {
            int c = wn*64 + j*16 + l15;
            scol[c] = fminf(scol[c], cvv[j]);
        }
    }
    __syncthreads();
    if (tid < 128)       rp[(size_t)bn * N_ROWS + m0 + tid] = srow[tid];
    else if (tid < 256)  cp[(size_t)bm * K_PROT + n0 + (tid - 128)] = scol[tid - 128];
}

// ---------------- K4: reduce partials (min over tiles, sqrt, sum) ----------------
__global__ __launch_bounds__(256) void k4_reduce(
    const float* __restrict__ rp, const float* __restrict__ cp,
    float* __restrict__ accw)
{
    __shared__ float sbuf[160];
    int b = blockIdx.x, t = threadIdx.x;
    int lane = t & 63, w = t >> 6;
    if (b < 64) {
        float a = 0.0f;
        #pragma unroll
        for (int rr = 0; rr < 2; rr++) {
            int row = b*512 + rr*256 + t;
            float m = 3.0e38f;
            #pragma unroll
            for (int k = 0; k < 16; k++) m = fminf(m, rp[(size_t)k * N_ROWS + row]);
            a += sqrtf(m);
        }
        #pragma unroll
        for (int d = 32; d >= 1; d >>= 1) a += __shfl_xor(a, d);
        if (lane == 0) sbuf[w] = a;
        __syncthreads();
        if (t == 0) atomicAdd(accw + 0, sbuf[0] + sbuf[1] + sbuf[2] + sbuf[3]);
    } else {
        int col  = (b - 64) * 128 + (t & 127);
        int half = t >> 7;
        float m = 3.0e38f;
        for (int k = half*128; k < half*128 + 128; k++)
            m = fminf(m, cp[(size_t)k * K_PROT + col]);
        if (half == 0) sbuf[t] = m;
        __syncthreads();
        if (half == 1) sbuf[t - 128] = fminf(sbuf[t - 128], m);
        __syncthreads();
        if (t < 128) {
            float s = sqrtf(sbuf[t]);
            #pragma unroll
            for (int d = 32; d >= 1; d >>= 1) s += __shfl_xor(s, d);
            if (lane == 0) sbuf[128 + (t >> 6)] = s;
        }
        __syncthreads();
        if (t == 0) atomicAdd(accw + 1, sbuf[128] + sbuf[129]);
    }
}

// ---------------- K5: finalize scalar outputs ----------------
__global__ void k5_final(
    const float* __restrict__ accw,
    const float* __restrict__ recon, const float* __restrict__ kl,
    const float* __restrict__ mmd, float* __restrict__ out)
{
    out[OUT_CVAE] = recon[0] + 0.5f*kl[0] + mmd[0];
    out[OUT_PROT] = 0.5f*(accw[0] / (float)N_ROWS) + 0.5f*(accw[1] / (float)K_PROT);
}

extern "C" void kernel_launch(void* const* d_in, const int* in_sizes, int n_in,
                              void* d_out, int out_size, void* d_ws, size_t ws_size,
                              hipStream_t stream)
{
    const float* Z     = (const float*)d_in[0];
    const float* P     = (const float*)d_in[1];
    const float* recon = (const float*)d_in[2];
    const float* kl    = (const float*)d_in[3];
    const float* mmd   = (const float*)d_in[4];
    float* out = (float*)d_out;
    float* ws  = (float*)d_ws;

    float* z2   = ws + WS_Z2;
    float* invn = ws + WS_INVN;
    float* p2   = ws + WS_P2;
    float* accw = ws + WS_ACC;
    float* rp   = ws + WS_RP;
    float* cp   = ws + WS_CP;
    __bf16* Zb = (__bf16*)(ws + WS_ZB);
    __bf16* Pb = (__bf16*)(ws + WS_PB);

    hipLaunchKernelGGL(k12_rows, dim3(N_ROWS/4 + K_PROT/4), dim3(256), 0, stream,
                       Z, P, out + OUT_X0, out + OUT_X1, z2, invn, Zb, p2, Pb, accw);
    hipLaunchKernelGGL(k3_gemm, dim3((N_ROWS/BM)*(K_PROT/BN)), dim3(256), 0, stream,
                       Zb, Pb, z2, p2, invn, out + OUT_XMAP, rp, cp);
    hipLaunchKernelGGL(k4_reduce, dim3(80), dim3(256), 0, stream, rp, cp, accw);
    hipLaunchKernelGGL(k5_final, dim3(1), dim3(1), 0, stream, accw, recon, kl, mmd, out);
}

// Round 8
// 427.744 us; speedup vs baseline: 1.2443x; 1.0529x over previous
//
#include <hip/hip_runtime.h>
#include <hip/hip_bf16.h>

typedef __bf16 bf16x8 __attribute__((ext_vector_type(8)));
typedef __bf16 bf16x4 __attribute__((ext_vector_type(4)));
typedef float  f32x4  __attribute__((ext_vector_type(4)));

#define N_ROWS 32768
#define D_DIM  256
#define K_PROT 2048

// ws layout (float offsets)
#define WS_Z2    0
#define WS_INVN  32768
#define WS_P2    65536
#define WS_ACC   67584                 // 2 floats (sum of row-mins, sum of col-mins)
#define WS_RP    67600                 // row-min partials [16][32768] f32 = 2 MB
#define WS_CP    (67600 + 524288)      // col-min partials [256][2048] f32 = 2 MB
#define WS_ZB    (67600 + 1048576)     // bf16 Z copy: 32768*256 bf16 (16B-aligned)
#define WS_PB    (67600 + 1048576 + 4194304)  // bf16 P copy

// out layout (float offsets)
#define OUT_X0   0UL
#define OUT_X1   8388608UL
#define OUT_XMAP 16777216UL
#define OUT_CVAE 83886080UL
#define OUT_PROT 83886081UL

__device__ __forceinline__ void gload16(const __bf16* gsrc, const __bf16* ldst) {
    auto g = (const __attribute__((address_space(1))) unsigned int*)(unsigned long long)gsrc;
    auto l = (__attribute__((address_space(3))) unsigned int*)(unsigned long long)ldst;
    __builtin_amdgcn_global_load_lds(g, l, 16, 0, 0);
}

// ---------------- K12: fused row prep for Z (norms, copies, bf16) and P (norms, bf16) ----------------
__global__ __launch_bounds__(256) void k12_rows(
    const float* __restrict__ Z, const float* __restrict__ P,
    float* __restrict__ out0, float* __restrict__ out1,
    float* __restrict__ z2, float* __restrict__ invn,
    __bf16* __restrict__ Zb,
    float* __restrict__ p2, __bf16* __restrict__ Pb,
    float* __restrict__ accw)
{
    int b    = blockIdx.x;
    int lane = threadIdx.x & 63;
    if (b == 0 && threadIdx.x < 2) accw[threadIdx.x] = 0.0f;   // init loss accumulators
    if (b < (N_ROWS/4)) {
        int row  = (b << 2) + (threadIdx.x >> 6);
        size_t base = (size_t)row * D_DIM;
        float4 v = ((const float4*)(Z + base))[lane];
        float ss = v.x*v.x + v.y*v.y + v.z*v.z + v.w*v.w;
        #pragma unroll
        for (int d = 32; d >= 1; d >>= 1) ss += __shfl_xor(ss, d);
        float inv = 1.0f / fmaxf(sqrtf(ss), 1e-12f);
        ((float4*)(out0 + base))[lane] = v;
        float4 xv; xv.x = v.x*inv; xv.y = v.y*inv; xv.z = v.z*inv; xv.w = v.w*inv;
        ((float4*)(out1 + base))[lane] = xv;
        bf16x4 bv; bv[0]=(__bf16)v.x; bv[1]=(__bf16)v.y; bv[2]=(__bf16)v.z; bv[3]=(__bf16)v.w;
        ((bf16x4*)(Zb + base))[lane] = bv;
        if (lane == 0) { z2[row] = ss; invn[row] = inv; }
    } else {
        int row  = ((b - (N_ROWS/4)) << 2) + (threadIdx.x >> 6);
        size_t base = (size_t)row * D_DIM;
        float4 v = ((const float4*)(P + base))[lane];
        float ss = v.x*v.x + v.y*v.y + v.z*v.z + v.w*v.w;
        #pragma unroll
        for (int d = 32; d >= 1; d >>= 1) ss += __shfl_xor(ss, d);
        bf16x4 bv; bv[0]=(__bf16)v.x; bv[1]=(__bf16)v.y; bv[2]=(__bf16)v.z; bv[3]=(__bf16)v.w;
        ((bf16x4*)(Pb + base))[lane] = bv;
        if (lane == 0) { p2[row] = ss; }
    }
}

// ---------------- K3: bf16 MFMA GEMM G = Zb * Pb^T + fused epilogue ----------------
// RESUBMIT of round-7 (container infra failure, no data; source audited clean:
// in-bounds, uniform barriers, bijective swizzle round-trip verified).
// Round-2 structure + ONE change: LDS XOR bank-swizzle.
// Diagnosis: [128][64] bf16 tiles have 128B rows -> ds_read_b128 fragment reads
// are bank-invariant in l15 -> 16-way conflict -> serialized LDS pipe; explains
// the four null/regressed scheduling experiments (rounds 0,1,2,6).
// Fix per rule #21 (gload_lds writes linearly): pre-swizzle the GLOBAL source
// chunk (q ^= row&7) and apply the same XOR on the read chunk index. Reader's
// 16 l15-lanes then cover all 8 chunk-positions -> 32 banks -> 2-way (free).
#define BM 128
#define BN 128
#define BK 64

__global__ __launch_bounds__(256, 3) void k3_gemm(
    const __bf16* __restrict__ Zb, const __bf16* __restrict__ Pb,
    const float* __restrict__ z2, const float* __restrict__ p2,
    const float* __restrict__ invn,
    float* __restrict__ xmap,
    float* __restrict__ rp, float* __restrict__ cp)
{
    __shared__ __bf16 As[BM * BK];   // 16 KB, rows of 128 B, contiguous (linear dest)
    __shared__ __bf16 Bs[BN * BK];   // 16 KB

    const int tid  = threadIdx.x;
    // XCD swizzle: hw-consecutive-mod-8 blocks (same XCD) -> contiguous logical chunk
    const int wg   = (blockIdx.x & 7) * 512 + (blockIdx.x >> 3);
    const int bn   = wg & 15;   // 16 n-blocks
    const int bm   = wg >> 4;   // 256 m-blocks
    const int lane = tid & 63;
    const int wave = tid >> 6;
    const int wm   = wave >> 1;
    const int wn   = wave & 1;
    const int l15  = lane & 15;
    const int quad = lane >> 4;

    const int m0 = bm * BM;
    const int n0 = bn * BN;

    f32x4 acc[4][4];
    #pragma unroll
    for (int i = 0; i < 4; i++)
        #pragma unroll
        for (int j = 0; j < 4; j++)
            #pragma unroll
            for (int r = 0; r < 4; r++) acc[i][j][r] = 0.0f;

    // staging: chunk c = (it*4+wave)*64 + lane (16B units); row = c>>3, q = c&7.
    // LDS gets linear chunk c; its CONTENT is global chunk (q ^ (row&7)) of the
    // same row -> LDS[row][q] = G[row][q ^ (row&7)] (XOR bijective within row).
    const int ch_row[4] = {
        ((0*4 + wave)*64 + lane) >> 3, ((1*4 + wave)*64 + lane) >> 3,
        ((2*4 + wave)*64 + lane) >> 3, ((3*4 + wave)*64 + lane) >> 3 };
    const int ch_c = lane & 7;
    const int ch_cs[4] = {
        ch_c ^ (ch_row[0] & 7), ch_c ^ (ch_row[1] & 7),
        ch_c ^ (ch_row[2] & 7), ch_c ^ (ch_row[3] & 7) };

    for (int kt = 0; kt < D_DIM; kt += BK) {
        #pragma unroll
        for (int it = 0; it < 4; it++) {
            const __bf16* aS = Zb + (size_t)(m0 + ch_row[it]) * D_DIM + kt + ch_cs[it] * 8;
            const __bf16* bS = Pb + (size_t)(n0 + ch_row[it]) * D_DIM + kt + ch_cs[it] * 8;
            gload16(aS, As + (it*4 + wave) * 512);
            gload16(bS, Bs + (it*4 + wave) * 512);
        }
        __syncthreads();   // drains vmcnt(0): staging visible

        #pragma unroll
        for (int s = 0; s < 2; s++) {
            bf16x8 af[4], bfr[4];
            #pragma unroll
            for (int i = 0; i < 4; i++) {
                int row = wm*64 + i*16 + l15;
                af[i] = *(const bf16x8*)(As + row * BK + (((s*4 + quad) ^ (row & 7)) * 8));
            }
            #pragma unroll
            for (int j = 0; j < 4; j++) {
                int row = wn*64 + j*16 + l15;
                bfr[j] = *(const bf16x8*)(Bs + row * BK + (((s*4 + quad) ^ (row & 7)) * 8));
            }
            #pragma unroll
            for (int i = 0; i < 4; i++)
                #pragma unroll
                for (int j = 0; j < 4; j++)
                    acc[i][j] = __builtin_amdgcn_mfma_f32_16x16x32_bf16(af[i], bfr[j], acc[i][j], 0, 0, 0);
        }
        __syncthreads();   // protect LDS before next stage
    }

    // ---- epilogue (identical to round 2) ----
    // C/D layout (m89-verified): col(n) = lane&15, row(m) = quad*4 + reg
    // Mins over SQUARED distances (sqrt is monotone, applied in k4); all values >= 0.
    float invr[16], zzr[16];
    #pragma unroll
    for (int i = 0; i < 4; i++)
        #pragma unroll
        for (int r = 0; r < 4; r++) {
            int gm = m0 + wm*64 + i*16 + quad*4 + r;
            invr[i*4+r] = invn[gm];
            zzr[i*4+r]  = z2[gm];
        }
    float pp[4];
    #pragma unroll
    for (int j = 0; j < 4; j++) pp[j] = p2[n0 + wn*64 + j*16 + l15];

    float cminv[4] = {3.0e38f, 3.0e38f, 3.0e38f, 3.0e38f};
    float rvv[16];

    #pragma unroll
    for (int i = 0; i < 4; i++) {
        #pragma unroll
        for (int r = 0; r < 4; r++) {
            int gm = m0 + wm*64 + i*16 + quad*4 + r;
            float zi = zzr[i*4+r], iv = invr[i*4+r];
            size_t orow = (size_t)gm * K_PROT + n0 + wn*64 + l15;
            float rv = 3.0e38f;
            #pragma unroll
            for (int j = 0; j < 4; j++) {
                float g = acc[i][j][r];
                xmap[orow + j*16] = g * iv;
                float d2 = fmaxf(zi + pp[j] - 2.0f*g, 0.0f);
                rv = fminf(rv, d2);
                cminv[j] = fminf(cminv[j], d2);
            }
            #pragma unroll
            for (int s = 1; s < 16; s <<= 1) rv = fminf(rv, __shfl_xor(rv, s));
            rvv[i*4+r] = rv;   // valid on all lanes (xor butterfly)
        }
    }
    float cvv[4];
    #pragma unroll
    for (int j = 0; j < 4; j++) {
        float cv = cminv[j];
        cv = fminf(cv, __shfl_xor(cv, 16));
        cv = fminf(cv, __shfl_xor(cv, 32));
        cvv[j] = cv;           // valid on all lanes
    }

    // block-level combine in LDS (As is dead after the K-loop's trailing barrier)
    float* srow = (float*)As;        // 128 row-mins
    float* scol = srow + 128;        // 128 col-mins
    if (wn == 0 && l15 == 0) {
        #pragma unroll
        for (int i = 0; i < 4; i++)
            #pragma unroll
            for (int r = 0; r < 4; r++)
                srow[wm*64 + i*16 + quad*4 + r] = rvv[i*4+r];
    }
    if (wm == 0 && quad == 0) {
        #pragma unroll
        for (int j = 0; j < 4; j++) scol[wn*64 + j*16 + l15] = cvv[j];
    }
    __syncthreads();
    if (wn == 1 && l15 == 0) {
        #pragma unroll
        for (int i = 0; i < 4; i++)
            #pragma unroll
            for (int r = 0; r < 4; r++) {
                int idx = wm*64 + i*16 + quad*4 + r;
                srow[idx] = fminf(srow[idx], rvv[i*4+r]);
            }
    }
    if (wm == 1 && quad == 0) {
        #pragma unroll
        for (int j = 0; j < 4; j++) {
            int c = wn*64 + j*16 + l15;
            scol[c] = fminf(scol[c], cvv[j]);
        }
    }
    __syncthreads();
    if (tid < 128)       rp[(size_t)bn * N_ROWS + m0 + tid] = srow[tid];
    else if (tid < 256)  cp[(size_t)bm * K_PROT + n0 + (tid - 128)] = scol[tid - 128];
}

// ---------------- K4: reduce partials (min over tiles, sqrt, sum) ----------------
__global__ __launch_bounds__(256) void k4_reduce(
    const float* __restrict__ rp, const float* __restrict__ cp,
    float* __restrict__ accw)
{
    __shared__ float sbuf[160];
    int b = blockIdx.x, t = threadIdx.x;
    int lane = t & 63, w = t >> 6;
    if (b < 64) {
        float a = 0.0f;
        #pragma unroll
        for (int rr = 0; rr < 2; rr++) {
            int row = b*512 + rr*256 + t;
            float m = 3.0e38f;
            #pragma unroll
            for (int k = 0; k < 16; k++) m = fminf(m, rp[(size_t)k * N_ROWS + row]);
            a += sqrtf(m);
        }
        #pragma unroll
        for (int d = 32; d >= 1; d >>= 1) a += __shfl_xor(a, d);
        if (lane == 0) sbuf[w] = a;
        __syncthreads();
        if (t == 0) atomicAdd(accw + 0, sbuf[0] + sbuf[1] + sbuf[2] + sbuf[3]);
    } else {
        int col  = (b - 64) * 128 + (t & 127);
        int half = t >> 7;
        float m = 3.0e38f;
        for (int k = half*128; k < half*128 + 128; k++)
            m = fminf(m, cp[(size_t)k * K_PROT + col]);
        if (half == 0) sbuf[t] = m;
        __syncthreads();
        if (half == 1) sbuf[t - 128] = fminf(sbuf[t - 128], m);
        __syncthreads();
        if (t < 128) {
            float s = sqrtf(sbuf[t]);
            #pragma unroll
            for (int d = 32; d >= 1; d >>= 1) s += __shfl_xor(s, d);
            if (lane == 0) sbuf[128 + (t >> 6)] = s;
        }
        __syncthreads();
        if (t == 0) atomicAdd(accw + 1, sbuf[128] + sbuf[129]);
    }
}

// ---------------- K5: finalize scalar outputs ----------------
__global__ void k5_final(
    const float* __restrict__ accw,
    const float* __restrict__ recon, const float* __restrict__ kl,
    const float* __restrict__ mmd, float* __restrict__ out)
{
    out[OUT_CVAE] = recon[0] + 0.5f*kl[0] + mmd[0];
    out[OUT_PROT] = 0.5f*(accw[0] / (float)N_ROWS) + 0.5f*(accw[1] / (float)K_PROT);
}

extern "C" void kernel_launch(void* const* d_in, const int* in_sizes, int n_in,
                              void* d_out, int out_size, void* d_ws, size_t ws_size,
                              hipStream_t stream)
{
    const float* Z     = (const float*)d_in[0];
    const float* P     = (const float*)d_in[1];
    const float* recon = (const float*)d_in[2];
    const float* kl    = (const float*)d_in[3];
    const float* mmd   = (const float*)d_in[4];
    float* out = (float*)d_out;
    float* ws  = (float*)d_ws;

    float* z2   = ws + WS_Z2;
    float* invn = ws + WS_INVN;
    float* p2   = ws + WS_P2;
    float* accw = ws + WS_ACC;
    float* rp   = ws + WS_RP;
    float* cp   = ws + WS_CP;
    __bf16* Zb = (__bf16*)(ws + WS_ZB);
    __bf16* Pb = (__bf16*)(ws + WS_PB);

    hipLaunchKernelGGL(k12_rows, dim3(N_ROWS/4 + K_PROT/4), dim3(256), 0, stream,
                       Z, P, out + OUT_X0, out + OUT_X1, z2, invn, Zb, p2, Pb, accw);
    hipLaunchKernelGGL(k3_gemm, dim3((N_ROWS/BM)*(K_PROT/BN)), dim3(256), 0, stream,
                       Zb, Pb, z2, p2, invn, out + OUT_XMAP, rp, cp);
    hipLaunchKernelGGL(k4_reduce, dim3(80), dim3(256), 0, stream, rp, cp, accw);
    hipLaunchKernelGGL(k5_final, dim3(1), dim3(1), 0, stream, accw, recon, kl, mmd, out);
}